// Round 1
// baseline (276.714 us; speedup 1.0000x reference)
//
#include <hip/hip_runtime.h>

#define N_BLOCKS 12
#define D 256
#define BATCH 8192

typedef __attribute__((ext_vector_type(8))) short bf16x8;   // 8 bf16 = 4 VGPRs
typedef __attribute__((ext_vector_type(4))) float f32x4;

// fp32 -> bf16 round-to-nearest-even (bit trick; inputs are finite)
__device__ __forceinline__ unsigned short f2bf(float f) {
  unsigned int u = __float_as_uint(f);
  u += 0x7fffu + ((u >> 16) & 1u);
  return (unsigned short)(u >> 16);
}

// async global->LDS, 16B per lane. LDS dest = wave-uniform base + lane*16.
__device__ __forceinline__ void gld16(const unsigned short* g, unsigned short* l) {
  __builtin_amdgcn_global_load_lds(
      (const __attribute__((address_space(1))) unsigned int*)g,
      (__attribute__((address_space(3))) unsigned int*)l,
      16, 0, 0);
}

// ---------------- Pass 1a: X fp32 -> bf16 (straight copy-convert) ----------
__global__ void cvt_x(const float* __restrict__ X, unsigned short* __restrict__ Xb) {
  const long long t = (long long)blockIdx.x * 256 + threadIdx.x;
  const long long base = t * 8;
  const float4 v0 = *(const float4*)(X + base);
  const float4 v1 = *(const float4*)(X + base + 4);
  uint4 r;
  r.x = (unsigned)f2bf(v0.x) | ((unsigned)f2bf(v0.y) << 16);
  r.y = (unsigned)f2bf(v0.z) | ((unsigned)f2bf(v0.w) << 16);
  r.z = (unsigned)f2bf(v1.x) | ((unsigned)f2bf(v1.y) << 16);
  r.w = (unsigned)f2bf(v1.z) | ((unsigned)f2bf(v1.w) << 16);
  *(uint4*)(Xb + base) = r;
}

// ------------- Pass 1b: W[k][i][o] fp32 -> Wt[k][o][i] bf16 (LDS transpose) -
__global__ void cvt_w(const float* __restrict__ W, unsigned short* __restrict__ Wt) {
  __shared__ unsigned short tile[32][33];   // +1 pad vs bank conflicts
  const int k  = blockIdx.x >> 6;
  const int t  = blockIdx.x & 63;
  const int ti = t >> 3;                    // tile row (i dim), 8 tiles
  const int tj = t & 7;                     // tile col (o dim)
  const float* Wk = W + (long long)k * D * D;
  unsigned short* Wtk = Wt + (long long)k * D * D;
  const int lx = threadIdx.x & 31, ly = threadIdx.x >> 5;   // 32x8
  #pragma unroll
  for (int r = 0; r < 4; ++r) {
    const int i = ti * 32 + ly + r * 8;
    const int o = tj * 32 + lx;
    tile[ly + r * 8][lx] = f2bf(Wk[i * D + o]);
  }
  __syncthreads();
  #pragma unroll
  for (int r = 0; r < 4; ++r) {
    const int o = tj * 32 + ly + r * 8;
    const int i = ti * 32 + lx;
    Wtk[o * D + i] = tile[lx][ly + r * 8];
  }
}

// ------------- Pass 2: block-sparse GEMM, BM=256, BN=128, BK=32 ------------
// T2+T3+T4+T5 stack (counted-vmcnt phase schedule, plain HIP):
//  - 3-deep LDS ring of K-tile slots (A 16KB + B 8KB each, 72KB total)
//    -> prefetch distance 2, boundary wait is vmcnt(3), never 0 in-loop.
//  - One barrier per K-tile: stages for tile t+2 target slot (t+2)%3 =
//    (t-1)%3; every wave finished reading tile t-1 before passing the
//    boundary barrier of tile t, so the overwrite is race-free.
//  - XOR swizzle vs ds_read bank conflicts: LDS holds logical 16B chunk c
//    of row r at slot c^(r&3). global_load_lds writes linearly, so the
//    inverse swizzle is applied to the per-lane GLOBAL source address
//    (rule: both-sides-or-neither); ds_read applies it on the read side.
//  - setprio(1) around the 16-MFMA cluster.
//  - 8 waves (4M x 2N), 64x64 per wave; 768 blocks = 8 XCD x 3 (i,n) pairs
//    x 32 m-tiles = exactly 3 rounds of 256 CUs at 2 blocks/CU.
//    Per-XCD B working set = 3 pairs x 256KB -> L2-resident.
__launch_bounds__(512, 4)
__global__ void bs_gemm(const unsigned short* __restrict__ Xb,
                        const unsigned short* __restrict__ Wt,
                        const float* __restrict__ bias,
                        const int* __restrict__ i_idx,
                        const int* __restrict__ j_idx,
                        int nact,
                        float* __restrict__ Y) {
  __shared__ unsigned short lds[3 * 12288];   // 3 slots x 24KB = 72KB

  // grid decode: bid&7 -> XCD (round-robin dispatch heuristic)
  const int bid   = blockIdx.x;
  const int xcd   = bid & 7;
  const int local = bid >> 3;            // 0..95
  const int pp    = local >> 5;          // 0..2
  const int bm    = local & 31;          // m-tile (batch/256)
  const int p     = xcd * 3 + pp;        // 0..23
  const int i     = p >> 1;              // output row
  const int bn    = p & 1;               // n-half (128 cols)

  // collect active blocks feeding output row i (pattern gives exactly 4)
  int ks0 = 0, ks1 = 0, ks2 = 0, ks3 = 0, js0 = 0, js1 = 0, js2 = 0, js3 = 0, nk = 0;
  for (int k = 0; k < nact; ++k) {
    if (i_idx[k] == i) {
      const int j = j_idx[k];
      if      (nk == 0) { ks0 = k; js0 = j; }
      else if (nk == 1) { ks1 = k; js1 = j; }
      else if (nk == 2) { ks2 = k; js2 = j; }
      else              { ks3 = k; js3 = j; }
      ++nk;
    }
  }
#define JS(t) ((t) == 0 ? js0 : (t) == 1 ? js1 : (t) == 2 ? js2 : js3)
#define KS(t) ((t) == 0 ? ks0 : (t) == 1 ? ks1 : (t) == 2 ? ks2 : ks3)

  const int tid  = threadIdx.x;
  const int wave = tid >> 6;
  const int lane = tid & 63;
  const int wm   = wave >> 1;            // 0..3 (m)
  const int wn   = wave & 1;             // 0..1 (n)
  const int q    = lane >> 4;            // k-quad, 0..3
  const int l15  = lane & 15;

  // --- staging: per-thread source (inverse-swizzled) + linear LDS dest ---
  // linear dest byte L: row = L>>6, slot16 = (L>>4)&3 ; holds logical chunk
  // c = slot16 ^ (row&3). 512 thr x 16B: A rows 0..255 (2 chunks), B rows 0..127.
  const int srow = tid >> 2;                         // 0..127
  const int sc   = (tid & 3) ^ (srow & 3);           // logical chunk to fetch
  const long long sA0 = (long long)srow * D + sc * 8;
  const long long sA1 = (long long)(srow + 128) * D + sc * 8;
  const long long sB0 = (long long)srow * D + sc * 8;
  const int dA0 = tid * 8;               // shorts: A rows 0..127
  const int dA1 = 4096 + tid * 8;        // A rows 128..255
  const int dB0 = 8192 + tid * 8;        // B rows 0..127

  // --- ds_read byte offsets within slot (swizzled) ---
  // logical chunk q of row r lives at byte r*64 + ((q ^ (r&3))<<4); r&3 == l15&3
  const int sw  = (q ^ (l15 & 3)) << 4;
  const int aR0 = (wm * 64 +  0 + l15) * 64 + sw;
  const int aR1 = (wm * 64 + 16 + l15) * 64 + sw;
  const int aR2 = (wm * 64 + 32 + l15) * 64 + sw;
  const int aR3 = (wm * 64 + 48 + l15) * 64 + sw;
  const int bR0 = 16384 + (wn * 64 +  0 + l15) * 64 + sw;
  const int bR1 = 16384 + (wn * 64 + 16 + l15) * 64 + sw;
  const int bR2 = 16384 + (wn * 64 + 32 + l15) * 64 + sw;
  const int bR3 = 16384 + (wn * 64 + 48 + l15) * 64 + sw;

  // stage K-tile st (0..31) into slot st%3. 3 loads/thread -> 3 vmcnt units.
  auto STAGE = [&](int st) {
    const int t  = st >> 3;              // active-block index
    const int kk = st & 7;               // k-quarter within block (BK=32)
    unsigned short* sl = lds + (st % 3) * 12288;
    const unsigned short* As =
        Xb + ((long long)JS(t) * BATCH + bm * 256) * D + kk * 32;
    const unsigned short* Bs =
        Wt + ((long long)KS(t) * D + bn * 128) * D + kk * 32;
    gld16(As + sA0, sl + dA0);
    gld16(As + sA1, sl + dA1);
    gld16(Bs + sB0, sl + dB0);
  };

  f32x4 acc[4][4] = {};

  STAGE(0);
  STAGE(1);

  #pragma unroll
  for (int kt = 0; kt < 32; ++kt) {
    // boundary: tile kt's 3 loads are the oldest outstanding (<=6 in flight);
    // vmcnt(3) retires them, leaves tile kt+1's 3 flying. Robust to extra
    // older vmem ops (oldest-first drain).
    if (kt == 31) asm volatile("s_waitcnt vmcnt(0)" ::: "memory");
    else          asm volatile("s_waitcnt vmcnt(3)" ::: "memory");
    __builtin_amdgcn_s_barrier();        // all waves' stages visible; all
    __builtin_amdgcn_sched_barrier(0);   // reads of tile kt-1 complete

    const char* sb = (const char*)(lds + (kt % 3) * 12288);
    bf16x8 aF[4], bF[4];
    aF[0] = *(const bf16x8*)(sb + aR0);
    aF[1] = *(const bf16x8*)(sb + aR1);
    aF[2] = *(const bf16x8*)(sb + aR2);
    aF[3] = *(const bf16x8*)(sb + aR3);
    bF[0] = *(const bf16x8*)(sb + bR0);
    bF[1] = *(const bf16x8*)(sb + bR1);
    bF[2] = *(const bf16x8*)(sb + bR2);
    bF[3] = *(const bf16x8*)(sb + bR3);

    if (kt < 30) STAGE(kt + 2);          // prefetch distance 2

    asm volatile("s_waitcnt lgkmcnt(0)" ::: "memory");
    __builtin_amdgcn_sched_barrier(0);   // rule #18: pin MFMA below the wait

    __builtin_amdgcn_s_setprio(1);
    #pragma unroll
    for (int mf = 0; mf < 4; ++mf)
      #pragma unroll
      for (int nf = 0; nf < 4; ++nf)
        acc[mf][nf] = __builtin_amdgcn_mfma_f32_16x16x32_bf16(
            aF[mf], bF[nf], acc[mf][nf], 0, 0, 0);
    __builtin_amdgcn_s_setprio(0);
  }

  // epilogue: C/D layout col=lane&15, row=quad*4+reg; bias folded here
  float* Yb = Y + (long long)i * BATCH * D;
  const int m0 = bm * 256 + wm * 64 + q * 4;
  const int n0 = bn * 128 + wn * 64 + l15;
  float bsum[4];
  #pragma unroll
  for (int nf = 0; nf < 4; ++nf) {
    float s = 0.f;
    for (int t = 0; t < nk; ++t) s += bias[KS(t) * D + n0 + nf * 16];
    bsum[nf] = s;
  }
  #pragma unroll
  for (int nf = 0; nf < 4; ++nf) {
    #pragma unroll
    for (int mf = 0; mf < 4; ++mf)
      #pragma unroll
      for (int r2 = 0; r2 < 4; ++r2)
        Yb[(long long)(m0 + mf * 16 + r2) * D + (n0 + nf * 16)] =
            acc[mf][nf][r2] + bsum[nf];
  }
#undef JS
#undef KS
}

extern "C" void kernel_launch(void* const* d_in, const int* in_sizes, int n_in,
                              void* d_out, int out_size, void* d_ws, size_t ws_size,
                              hipStream_t stream) {
  const float* X = (const float*)d_in[0];
  const float* W = (const float*)d_in[1];
  const float* b = (const float*)d_in[2];
  const int* i_idx = (const int*)d_in[3];
  const int* j_idx = (const int*)d_in[4];
  float* Y = (float*)d_out;
  const int nact = in_sizes[3];   // 48

  // workspace layout: Xb (50 MB bf16) | Wt (6 MB bf16, transposed)
  unsigned short* Xb = (unsigned short*)d_ws;
  unsigned short* Wt = (unsigned short*)((char*)d_ws + (size_t)N_BLOCKS * BATCH * D * 2);

  cvt_x<<<(N_BLOCKS * BATCH * D) / (256 * 8), 256, 0, stream>>>(X, Xb);
  cvt_w<<<nact * 64, 256, 0, stream>>>(W, Wt);
  bs_gemm<<<N_BLOCKS * 32 * 2, 512, 0, stream>>>(Xb, Wt, b, i_idx, j_idx, nact, Y);
}

// Round 2
// 260.145 us; speedup vs baseline: 1.0637x; 1.0637x over previous
//
#include <hip/hip_runtime.h>

#define N_BLOCKS 12
#define D 256
#define BATCH 8192

typedef __attribute__((ext_vector_type(8))) short bf16x8;   // 8 bf16 = 4 VGPRs
typedef __attribute__((ext_vector_type(4))) float f32x4;

// fp32 -> bf16 round-to-nearest-even (bit trick; inputs are finite)
__device__ __forceinline__ unsigned short f2bf(float f) {
  unsigned int u = __float_as_uint(f);
  u += 0x7fffu + ((u >> 16) & 1u);
  return (unsigned short)(u >> 16);
}

// async global->LDS, 16B per lane. LDS dest = wave-uniform base + lane*16.
__device__ __forceinline__ void gld16(const unsigned short* g, unsigned short* l) {
  __builtin_amdgcn_global_load_lds(
      (const __attribute__((address_space(1))) unsigned int*)g,
      (__attribute__((address_space(3))) unsigned int*)l,
      16, 0, 0);
}

// ---------------- Pass 1a: X fp32 -> bf16 (straight copy-convert) ----------
__global__ void cvt_x(const float* __restrict__ X, unsigned short* __restrict__ Xb) {
  const long long t = (long long)blockIdx.x * 256 + threadIdx.x;
  const long long base = t * 8;
  const float4 v0 = *(const float4*)(X + base);
  const float4 v1 = *(const float4*)(X + base + 4);
  uint4 r;
  r.x = (unsigned)f2bf(v0.x) | ((unsigned)f2bf(v0.y) << 16);
  r.y = (unsigned)f2bf(v0.z) | ((unsigned)f2bf(v0.w) << 16);
  r.z = (unsigned)f2bf(v1.x) | ((unsigned)f2bf(v1.y) << 16);
  r.w = (unsigned)f2bf(v1.z) | ((unsigned)f2bf(v1.w) << 16);
  *(uint4*)(Xb + base) = r;
}

// ------------- Pass 1b: W[k][i][o] fp32 -> Wt[k][o][i] bf16 (LDS transpose) -
__global__ void cvt_w(const float* __restrict__ W, unsigned short* __restrict__ Wt) {
  __shared__ unsigned short tile[32][33];   // +1 pad vs bank conflicts
  const int k  = blockIdx.x >> 6;
  const int t  = blockIdx.x & 63;
  const int ti = t >> 3;                    // tile row (i dim), 8 tiles
  const int tj = t & 7;                     // tile col (o dim)
  const float* Wk = W + (long long)k * D * D;
  unsigned short* Wtk = Wt + (long long)k * D * D;
  const int lx = threadIdx.x & 31, ly = threadIdx.x >> 5;   // 32x8
  #pragma unroll
  for (int r = 0; r < 4; ++r) {
    const int i = ti * 32 + ly + r * 8;
    const int o = tj * 32 + lx;
    tile[ly + r * 8][lx] = f2bf(Wk[i * D + o]);
  }
  __syncthreads();
  #pragma unroll
  for (int r = 0; r < 4; ++r) {
    const int o = tj * 32 + ly + r * 8;
    const int i = ti * 32 + lx;
    Wtk[o * D + i] = tile[lx][ly + r * 8];
  }
}

// ------------- Pass 2: block-sparse GEMM, BM=BN=128, BK=32 -----------------
// R0's locality + R1's pipeline, combined:
//  - R0 XCD decode (bid&7 -> XCD, each XCD owns an 8-wide bm slice for all
//    (i,bn)): per-(i,XCD) working set = A 2MB + B 0.5MB -> L2-resident
//    staging (R0 measured FETCH 74MB vs R1's 197MB).
//  - 5-slot LDS ring (16KB/slot, 80KB), prefetch distance 4, ONE barrier
//    per K-tile, steady-state wait vmcnt(6) -- never 0 in-loop (T3+T4).
//    Race-free: stage for tile kt+4 targets slot (kt-1)%5, whose reads all
//    waves completed before passing barrier kt.
//  - Linear LDS layout, NO swizzle: R0(linear) and R1(swizzled) showed the
//    identical SQ_LDS_BANK_CONFLICT (4/read) -> intrinsic b128 wave64 cost.
//  - setprio(1) around the MFMA cluster (T5); sched_barrier fences (rule 18).
//  - 512 thr / 8 waves (4m x 2n), 32x64 per wave; 2 loads/thread/tile.
//    Grid 1536 = 8 XCD x 12 i x 8 bm_local x 2 bn; 2 blocks/CU (LDS-capped).
__launch_bounds__(512, 4)
__global__ void bs_gemm(const unsigned short* __restrict__ Xb,
                        const unsigned short* __restrict__ Wt,
                        const float* __restrict__ bias,
                        const int* __restrict__ i_idx,
                        const int* __restrict__ j_idx,
                        int nact,
                        float* __restrict__ Y) {
  __shared__ unsigned short lds[5 * 8192];   // 5 slots x 16KB = 80KB

  // R0's XCD-aware decode (dispatch round-robin heuristic)
  const int bid = blockIdx.x;
  const int x   = bid & 7;              // XCD slot
  const int r   = bid >> 3;             // 0..191 within XCD
  const int i   = r >> 4;               // output row (12)
  const int rem = r & 15;
  const int bm  = x * 8 + (rem >> 1);   // this XCD's 8-wide bm slice (128-row)
  const int bn  = rem & 1;

  // collect active blocks feeding output row i (pattern gives exactly 4)
  int ks0 = 0, ks1 = 0, ks2 = 0, ks3 = 0, js0 = 0, js1 = 0, js2 = 0, js3 = 0, nk = 0;
  for (int k = 0; k < nact; ++k) {
    if (i_idx[k] == i) {
      const int j = j_idx[k];
      if      (nk == 0) { ks0 = k; js0 = j; }
      else if (nk == 1) { ks1 = k; js1 = j; }
      else if (nk == 2) { ks2 = k; js2 = j; }
      else              { ks3 = k; js3 = j; }
      ++nk;
    }
  }
#define JS(t) ((t) == 0 ? js0 : (t) == 1 ? js1 : (t) == 2 ? js2 : js3)
#define KS(t) ((t) == 0 ? ks0 : (t) == 1 ? ks1 : (t) == 2 ? ks2 : ks3)

  const int tid  = threadIdx.x;
  const int wave = tid >> 6;
  const int lane = tid & 63;
  const int wm   = wave >> 1;            // 0..3 (m quarter, 32 rows)
  const int wn   = wave & 1;             // 0..1 (n half, 64 cols)
  const int q    = lane >> 4;            // k-quad, 0..3
  const int l15  = lane & 15;

  // staging: 512 thr x 16B = 8KB = one 128x32 bf16 tile per instruction.
  // row = tid>>2 (stride D in global), chunk = (tid&3)*8 elems.
  const int g_off = (tid >> 2) * D + (tid & 3) * 8;
  const int dA = tid * 8;                // shorts; A tile at slot base
  const int dB = 4096 + tid * 8;         // B tile at slot +8KB

  // ds_read byte offsets within slot (linear layout, row*64B + q*16B)
  const int aR0 = (wm * 32 +  0 + l15) * 64 + q * 16;
  const int aR1 = (wm * 32 + 16 + l15) * 64 + q * 16;
  const int bB  = 8192;
  const int bR0 = bB + (wn * 64 +  0 + l15) * 64 + q * 16;
  const int bR1 = bB + (wn * 64 + 16 + l15) * 64 + q * 16;
  const int bR2 = bB + (wn * 64 + 32 + l15) * 64 + q * 16;
  const int bR3 = bB + (wn * 64 + 48 + l15) * 64 + q * 16;

  // stage K-tile st (0..31) into slot st%5. 2 loads/thread -> 2 vmcnt units.
  auto STAGE = [&](int st) {
    const int t  = st >> 3;              // active-block index (compile-time)
    const int kk = st & 7;               // k-quarter within block (BK=32)
    unsigned short* sl = lds + (st % 5) * 8192;
    const unsigned short* As =
        Xb + ((long long)JS(t) * BATCH + bm * 128) * D + kk * 32 + g_off;
    const unsigned short* Bs =
        Wt + ((long long)KS(t) * D + bn * 128) * D + kk * 32 + g_off;
    gld16(As, sl + dA);
    gld16(Bs, sl + dB);
  };

  f32x4 acc[2][4] = {};

  STAGE(0); STAGE(1); STAGE(2); STAGE(3);   // 8 loads in flight

  #pragma unroll
  for (int kt = 0; kt < 32; ++kt) {
    // Retire tile kt's 2 loads; leave up to 3 tiles (6 loads) flying.
    if      (kt <= 28) asm volatile("s_waitcnt vmcnt(6)" ::: "memory");
    else if (kt == 29) asm volatile("s_waitcnt vmcnt(4)" ::: "memory");
    else if (kt == 30) asm volatile("s_waitcnt vmcnt(2)" ::: "memory");
    else               asm volatile("s_waitcnt vmcnt(0)" ::: "memory");
    __builtin_amdgcn_s_barrier();        // all waves' tile-kt stages visible;
    __builtin_amdgcn_sched_barrier(0);   // all reads of tile kt-1 complete

    const char* sb = (const char*)lds + (kt % 5) * 16384;
    bf16x8 aF[2], bF[4];
    aF[0] = *(const bf16x8*)(sb + aR0);
    aF[1] = *(const bf16x8*)(sb + aR1);
    bF[0] = *(const bf16x8*)(sb + bR0);
    bF[1] = *(const bf16x8*)(sb + bR1);
    bF[2] = *(const bf16x8*)(sb + bR2);
    bF[3] = *(const bf16x8*)(sb + bR3);

    if (kt < 28) STAGE(kt + 4);          // prefetch distance 4

    asm volatile("s_waitcnt lgkmcnt(0)" ::: "memory");
    __builtin_amdgcn_sched_barrier(0);   // rule #18: pin MFMA below the wait

    __builtin_amdgcn_s_setprio(1);
    #pragma unroll
    for (int mf = 0; mf < 2; ++mf)
      #pragma unroll
      for (int nf = 0; nf < 4; ++nf)
        acc[mf][nf] = __builtin_amdgcn_mfma_f32_16x16x32_bf16(
            aF[mf], bF[nf], acc[mf][nf], 0, 0, 0);
    __builtin_amdgcn_s_setprio(0);
  }

  // epilogue: C/D layout col=lane&15, row=quad*4+reg; bias folded here
  float* Yb = Y + (long long)i * BATCH * D;
  const int m0 = bm * 128 + wm * 32 + q * 4;
  const int n0 = bn * 128 + wn * 64 + l15;
  float bsum[4];
  #pragma unroll
  for (int nf = 0; nf < 4; ++nf) {
    float s = 0.f;
    for (int t = 0; t < nk; ++t) s += bias[KS(t) * D + n0 + nf * 16];
    bsum[nf] = s;
  }
  #pragma unroll
  for (int nf = 0; nf < 4; ++nf) {
    #pragma unroll
    for (int mf = 0; mf < 2; ++mf)
      #pragma unroll
      for (int r2 = 0; r2 < 4; ++r2)
        Yb[(long long)(m0 + mf * 16 + r2) * D + (n0 + nf * 16)] =
            acc[mf][nf][r2] + bsum[nf];
  }
#undef JS
#undef KS
}

extern "C" void kernel_launch(void* const* d_in, const int* in_sizes, int n_in,
                              void* d_out, int out_size, void* d_ws, size_t ws_size,
                              hipStream_t stream) {
  const float* X = (const float*)d_in[0];
  const float* W = (const float*)d_in[1];
  const float* b = (const float*)d_in[2];
  const int* i_idx = (const int*)d_in[3];
  const int* j_idx = (const int*)d_in[4];
  float* Y = (float*)d_out;
  const int nact = in_sizes[3];   // 48

  // workspace layout: Xb (48 MB bf16) | Wt (6 MB bf16, transposed)
  unsigned short* Xb = (unsigned short*)d_ws;
  unsigned short* Wt = (unsigned short*)((char*)d_ws + (size_t)N_BLOCKS * BATCH * D * 2);

  cvt_x<<<(N_BLOCKS * BATCH * D) / (256 * 8), 256, 0, stream>>>(X, Xb);
  cvt_w<<<nact * 64, 256, 0, stream>>>(W, Wt);
  bs_gemm<<<N_BLOCKS * 64 * 2, 512, 0, stream>>>(Xb, Wt, b, i_idx, j_idx, nact, Y);
}